// Round 1
// baseline (124.266 us; speedup 1.0000x reference)
//
#include <hip/hip_runtime.h>

#define N 8192
#define D 256
#define INV_TAU 14.285714285714286f
#define EPSN 1e-6f

// fused-lse kernel geometry
#define RT 128            // rows per block (4 waves x 32 rows)
#define CT 64             // cols per LDS tile
#define CSPLIT 16         // column splits across blocks
#define CPB (N / CSPLIT)  // 512 cols per block
#define NTILES (CPB / CT) // 8 tiles
#define LDSS 264          // ushorts per LDS row: 256 + 8 pad (528 B, 16B aligned)

typedef unsigned int u32x4 __attribute__((ext_vector_type(4)));
typedef __bf16 bf16x8 __attribute__((ext_vector_type(8)));
typedef float f32x4 __attribute__((ext_vector_type(4)));

__device__ inline unsigned short f2bf(float x) {
    unsigned int u = __builtin_bit_cast(unsigned int, x);
    u += 0x7fffu + ((u >> 16) & 1u);   // round-to-nearest-even (finite inputs)
    return (unsigned short)(u >> 16);
}

// One wave per row: normalize im/rec rows -> bf16, fp32 diag, zero rowsum.
__global__ void ntx_prep(const float* __restrict__ im, const float* __restrict__ rec,
                         unsigned short* __restrict__ A, unsigned short* __restrict__ Bm,
                         float* __restrict__ diag, float* __restrict__ rowsum) {
    const int wave = threadIdx.x >> 6;
    const int lane = threadIdx.x & 63;
    const int row  = blockIdx.x * 4 + wave;

    const float4 a = ((const float4*)(im  + (size_t)row * D))[lane];
    const float4 b = ((const float4*)(rec + (size_t)row * D))[lane];

    float ssa = a.x*a.x + a.y*a.y + a.z*a.z + a.w*a.w;
    float ssb = b.x*b.x + b.y*b.y + b.z*b.z + b.w*b.w;
    float dt  = a.x*b.x + a.y*b.y + a.z*b.z + a.w*b.w;
    #pragma unroll
    for (int o = 32; o; o >>= 1) {
        ssa += __shfl_xor(ssa, o);
        ssb += __shfl_xor(ssb, o);
        dt  += __shfl_xor(dt , o);
    }
    const float ra = 1.0f / fmaxf(sqrtf(ssa), EPSN);
    const float rb = 1.0f / fmaxf(sqrtf(ssb), EPSN);

    ushort4 pa, pb;
    pa.x = f2bf(a.x*ra); pa.y = f2bf(a.y*ra); pa.z = f2bf(a.z*ra); pa.w = f2bf(a.w*ra);
    pb.x = f2bf(b.x*rb); pb.y = f2bf(b.y*rb); pb.z = f2bf(b.z*rb); pb.w = f2bf(b.w*rb);
    *(ushort4*)(A  + (size_t)row * D + lane * 4) = pa;
    *(ushort4*)(Bm + (size_t)row * D + lane * 4) = pb;

    if (lane == 0) {
        diag[row]   = dt * ra * rb * INV_TAU;  // fp32 i2r[i,i]
        rowsum[row] = 0.0f;                    // ws is poisoned each launch
    }
}

// Fused GEMM + masked sum-of-exp per row.
// grid = (N/RT) * CSPLIT blocks of 256 threads (4 waves).
// blockIdx: rowblk = bid & 63, colblk = bid >> 6 (row-major so co-launched
// blocks share the same B slab in L2).
__global__ __launch_bounds__(256, 2)
void ntx_lse(const unsigned short* __restrict__ A, const unsigned short* __restrict__ Bm,
             const int* __restrict__ labels, float* __restrict__ rowsum) {
    __shared__ __align__(16) unsigned short Bs[CT][LDSS];  // ~33 KB

    const int wave = threadIdx.x >> 6;
    const int lane = threadIdx.x & 63;
    const int g    = lane >> 4;    // 0..3 (k-quad / row-quad)
    const int n16  = lane & 15;    // 0..15

    const int rowblk = blockIdx.x & (N / RT - 1);   // 0..63
    const int colblk = blockIdx.x >> 6;             // 0..15
    const int row0 = rowblk * RT + wave * 32;       // this wave's 32 rows
    const int col0 = colblk * CPB;

    // A fragments for 32 rows x K=256, held in registers (64 VGPRs).
    // A-operand layout: m = lane&15, k = (lane>>4)*8 + j
    bf16x8 afrag[2][8];
    #pragma unroll
    for (int rs = 0; rs < 2; ++rs) {
        const int r = row0 + rs * 16 + n16;
        #pragma unroll
        for (int k = 0; k < 8; ++k)
            afrag[rs][k] = __builtin_bit_cast(
                bf16x8, *(const u32x4*)(A + (size_t)r * D + k * 32 + g * 8));
    }

    // labels of this lane's 8 accumulation rows (C layout rows)
    int rlab[2][4];
    #pragma unroll
    for (int rs = 0; rs < 2; ++rs)
        #pragma unroll
        for (int q = 0; q < 4; ++q)
            rlab[rs][q] = labels[row0 + rs * 16 + g * 4 + q];

    float acc[2][4] = {{0.f,0.f,0.f,0.f},{0.f,0.f,0.f,0.f}};

    const int c32 = threadIdx.x & 31;   // 16B chunk within a 512B row
    const int rr  = threadIdx.x >> 5;   // 0..7

    for (int t = 0; t < NTILES; ++t) {
        const int colt = col0 + t * CT;
        // stage B tile: 64 cols x 512B, coalesced 16B/lane
        #pragma unroll
        for (int p = 0; p < 8; ++p) {
            const int br = p * 8 + rr;
            u32x4 v = *(const u32x4*)(Bm + (size_t)(colt + br) * D + c32 * 8);
            *(u32x4*)(&Bs[br][c32 * 8]) = v;
        }
        __syncthreads();

        #pragma unroll
        for (int cs = 0; cs < 4; ++cs) {
            // B-operand layout: n = lane&15, k = (lane>>4)*8 + j
            const int bc = cs * 16 + n16;
            bf16x8 bfrag[8];
            #pragma unroll
            for (int k = 0; k < 8; ++k)
                bfrag[k] = __builtin_bit_cast(
                    bf16x8, *(const u32x4*)(&Bs[bc][k * 32 + g * 8]));

            const int col  = colt + cs * 16 + n16;  // C layout: col = lane&15
            const int clab = labels[col];

            #pragma unroll
            for (int rs = 0; rs < 2; ++rs) {
                f32x4 c = {0.f, 0.f, 0.f, 0.f};
                #pragma unroll
                for (int k = 0; k < 8; ++k)
                    c = __builtin_amdgcn_mfma_f32_16x16x32_bf16(
                            afrag[rs][k], bfrag[k], c, 0, 0, 0);
                // epilogue: exp + mask + row partial sum
                #pragma unroll
                for (int q = 0; q < 4; ++q) {
                    const int r = row0 + rs * 16 + g * 4 + q;
                    const float e = __expf(c[q] * INV_TAU);
                    const bool drop = (rlab[rs][q] == clab) && (r != col);
                    acc[rs][q] += drop ? 0.0f : e;
                }
            }
        }
        __syncthreads();
    }

    // reduce partial row sums across the 16 lanes sharing each row group
    #pragma unroll
    for (int rs = 0; rs < 2; ++rs)
        #pragma unroll
        for (int q = 0; q < 4; ++q) {
            float v = acc[rs][q];
            v += __shfl_xor(v, 1);
            v += __shfl_xor(v, 2);
            v += __shfl_xor(v, 4);
            v += __shfl_xor(v, 8);
            if (n16 == 0)
                atomicAdd(&rowsum[row0 + rs * 16 + g * 4 + q], v);
        }
}

// loss = mean(log(rowsum) - diag)
__global__ void ntx_finish(const float* __restrict__ diag,
                           const float* __restrict__ rowsum,
                           float* __restrict__ out) {
    __shared__ float red[256];
    float s = 0.f;
    for (int i = threadIdx.x; i < N; i += 256)
        s += logf(rowsum[i]) - diag[i];
    red[threadIdx.x] = s;
    __syncthreads();
    #pragma unroll
    for (int o = 128; o; o >>= 1) {
        if (threadIdx.x < o) red[threadIdx.x] += red[threadIdx.x + o];
        __syncthreads();
    }
    if (threadIdx.x == 0) out[0] = red[0] / (float)N;
}

extern "C" void kernel_launch(void* const* d_in, const int* in_sizes, int n_in,
                              void* d_out, int out_size, void* d_ws, size_t ws_size,
                              hipStream_t stream) {
    const float* im     = (const float*)d_in[0];
    const float* rec    = (const float*)d_in[1];
    const int*   labels = (const int*)d_in[2];
    float* out = (float*)d_out;

    unsigned short* A  = (unsigned short*)d_ws;           // 4 MB bf16 im_n
    unsigned short* Bm = A + (size_t)N * D;               // 4 MB bf16 rec_n
    float* diag   = (float*)(Bm + (size_t)N * D);         // 32 KB
    float* rowsum = diag + N;                             // 32 KB

    ntx_prep<<<N / 4, 256, 0, stream>>>(im, rec, A, Bm, diag, rowsum);
    ntx_lse<<<(N / RT) * CSPLIT, 256, 0, stream>>>(A, Bm, labels, rowsum);
    ntx_finish<<<1, 256, 0, stream>>>(diag, rowsum, out);
}